// Round 8
// baseline (744.956 us; speedup 1.0000x reference)
//
#include <hip/hip_runtime.h>
#include <math.h>

// HashGridEncoder, FUSED single kernel.
// Block = 256-point chunk. Loop over 16 levels; all resident blocks tend to
// process the same level concurrently (level-major in TIME), keeping each
// level's 4 MiB table L2-resident per XCD. Per-thread results staged in LDS
// [256][33]; one fully-coalesced 32 KB float4 out write per block at the end.
// No scratch, no second pass.

static constexpr unsigned T_SZ  = 524288u;      // 2^19
static constexpr unsigned TMASK = T_SZ - 1u;
static constexpr int      LVLS  = 16;
static constexpr unsigned PI1   = 2654435761u;
static constexpr unsigned PI2   = 805459861u;

struct HGParams {
  float cell[LVLS];   // (float)(2.0 / res)
  float inv[LVLS];    // 1.0f / cell
};

__device__ __forceinline__ void encode_one_level(
    float x, float y, float z, float cell, float inv,
    const float2* __restrict__ tb, float& s0, float& s1) {
  const float fx = floorf((x + 1.0f) * inv);
  const float fy = floorf((y + 1.0f) * inv);
  const float fz = floorf((z + 1.0f) * inv);
  const float dx = (x - (fx * cell - 1.0f)) * inv;
  const float dy = (y - (fy * cell - 1.0f)) * inv;
  const float dz = (z - (fz * cell - 1.0f)) * inv;

  const unsigned hx0 = (unsigned)(int)fx;           // * PI0 = 1
  const unsigned hy0 = (unsigned)(int)fy * PI1;
  const unsigned hz0 = (unsigned)(int)fz * PI2;
  const unsigned hx1 = hx0 + 1u;
  const unsigned hy1 = hy0 + PI1;
  const unsigned hz1 = hz0 + PI2;

  const unsigned i000 = (hx0 ^ hy0 ^ hz0) & TMASK;
  const unsigned i001 = (hx0 ^ hy0 ^ hz1) & TMASK;
  const unsigned i010 = (hx0 ^ hy1 ^ hz0) & TMASK;
  const unsigned i011 = (hx0 ^ hy1 ^ hz1) & TMASK;
  const unsigned i100 = (hx1 ^ hy0 ^ hz0) & TMASK;
  const unsigned i101 = (hx1 ^ hy0 ^ hz1) & TMASK;
  const unsigned i110 = (hx1 ^ hy1 ^ hz0) & TMASK;
  const unsigned i111 = (hx1 ^ hy1 ^ hz1) & TMASK;

  const float2 e000 = tb[i000];
  const float2 e001 = tb[i001];
  const float2 e010 = tb[i010];
  const float2 e011 = tb[i011];
  const float2 e100 = tb[i100];
  const float2 e101 = tb[i101];
  const float2 e110 = tb[i110];
  const float2 e111 = tb[i111];

  const float ax = 1.0f - dx, ay = 1.0f - dy, az = 1.0f - dz;
  const float w00 = ax * ay, w01 = ax * dy, w10 = dx * ay, w11 = dx * dy;
  const float w000 = w00 * az, w001 = w00 * dz;
  const float w010 = w01 * az, w011 = w01 * dz;
  const float w100 = w10 * az, w101 = w10 * dz;
  const float w110 = w11 * az, w111 = w11 * dz;

  s0 = w000 * e000.x;
  s1 = w000 * e000.y;
  s0 = fmaf(w001, e001.x, s0); s1 = fmaf(w001, e001.y, s1);
  s0 = fmaf(w010, e010.x, s0); s1 = fmaf(w010, e010.y, s1);
  s0 = fmaf(w011, e011.x, s0); s1 = fmaf(w011, e011.y, s1);
  s0 = fmaf(w100, e100.x, s0); s1 = fmaf(w100, e100.y, s1);
  s0 = fmaf(w101, e101.x, s0); s1 = fmaf(w101, e101.y, s1);
  s0 = fmaf(w110, e110.x, s0); s1 = fmaf(w110, e110.y, s1);
  s0 = fmaf(w111, e111.x, s0); s1 = fmaf(w111, e111.y, s1);
}

__global__ __launch_bounds__(256) void hg_fused(
    const float* __restrict__ xyz,
    const float* __restrict__ tables,
    float4* __restrict__ out4,
    int n, HGParams P) {
  __shared__ float s[256][33];                 // 33: write 2-way max (free)
  const int t  = threadIdx.x;
  const int p0 = blockIdx.x * 256;
  const int p  = p0 + t;
  const bool live = (p < n);

  float x = 0.f, y = 0.f, z = 0.f;
  if (live) {
    x = xyz[3 * (size_t)p + 0];
    y = xyz[3 * (size_t)p + 1];
    z = xyz[3 * (size_t)p + 2];
  }

  // Level loop: each thread writes only its own LDS row -> no sync inside.
#pragma unroll
  for (int l = 0; l < LVLS; ++l) {
    const float2* __restrict__ tb = (const float2*)tables + (size_t)l * T_SZ;
    float s0, s1;
    encode_one_level(x, y, z, P.cell[l], P.inv[l], tb, s0, s1);
    s[t][2 * l + 0] = s0;
    s[t][2 * l + 1] = s1;
  }
  __syncthreads();

  // Coalesced 32 KB block write: 2048 float4, 8 per thread.
#pragma unroll
  for (int j = 0; j < 8; ++j) {
    const int w   = j * 256 + t;
    const int row = w >> 3;                    // point within chunk
    const int c4  = w & 7;                     // float4 within out row
    if (p0 + row < n)
      out4[(size_t)(p0 + row) * 8 + c4] =
          make_float4(s[row][4 * c4 + 0], s[row][4 * c4 + 1],
                      s[row][4 * c4 + 2], s[row][4 * c4 + 3]);
  }
}

extern "C" void kernel_launch(void* const* d_in, const int* in_sizes, int n_in,
                              void* d_out, int out_size, void* d_ws, size_t ws_size,
                              hipStream_t stream) {
  const float* xyz    = (const float*)d_in[0];
  const float* tables = (const float*)d_in[1];
  float* out = (float*)d_out;
  const int n = in_sizes[0] / 3;

  // Replicate Python's RES computation bit-for-bit (same glibc libm doubles).
  HGParams P;
  const double B = exp((log(2048.0) - log(16.0)) / 15.0);
  for (int i = 0; i < LVLS; ++i) {
    const int r = (int)floor(16.0 * pow(B, (double)i));
    const double cd = 2.0 / (double)r;
    P.cell[i] = (float)cd;
    P.inv[i]  = 1.0f / P.cell[i];
  }

  const int nc = (n + 255) / 256;
  hg_fused<<<nc, 256, 0, stream>>>(xyz, tables, (float4*)out, n, P);
}

// Round 9
// 655.783 us; speedup vs baseline: 1.1360x; 1.1360x over previous
//
#include <hip/hip_runtime.h>
#include <math.h>

// HashGridEncoder, level-major two-pass (fusion falsified in R8: drift ->
// 4.5x FETCH. Separate dispatch = free phase-locking).
// Pass 1 (hg_gather): all resident blocks share one level -> 4 MiB table per
//   XCD L2. Scratch chunk-major [chunk][LVLS][256] float2, coalesced writes.
// Pass 2 (hg_transpose_reg): register-only transpose, no LDS/sync. Thread =
//   point: 16 coalesced 8B loads, 8 float4 stores (thread owns its 128B row).
// Fallback (hg_encode): point-major single kernel if ws too small.

static constexpr unsigned T_SZ  = 524288u;      // 2^19
static constexpr unsigned TMASK = T_SZ - 1u;
static constexpr int      LVLS  = 16;
static constexpr unsigned PI1   = 2654435761u;
static constexpr unsigned PI2   = 805459861u;

struct HGParams {
  float cell[LVLS];   // (float)(2.0 / res)
  float inv[LVLS];    // 1.0f / cell
};

__device__ __forceinline__ void encode_one_level(
    float x, float y, float z, float cell, float inv,
    const float2* __restrict__ tb, float& s0, float& s1) {
  const float fx = floorf((x + 1.0f) * inv);
  const float fy = floorf((y + 1.0f) * inv);
  const float fz = floorf((z + 1.0f) * inv);
  const float dx = (x - (fx * cell - 1.0f)) * inv;
  const float dy = (y - (fy * cell - 1.0f)) * inv;
  const float dz = (z - (fz * cell - 1.0f)) * inv;

  const unsigned hx0 = (unsigned)(int)fx;           // * PI0 = 1
  const unsigned hy0 = (unsigned)(int)fy * PI1;
  const unsigned hz0 = (unsigned)(int)fz * PI2;
  const unsigned hx1 = hx0 + 1u;
  const unsigned hy1 = hy0 + PI1;
  const unsigned hz1 = hz0 + PI2;

  const unsigned i000 = (hx0 ^ hy0 ^ hz0) & TMASK;
  const unsigned i001 = (hx0 ^ hy0 ^ hz1) & TMASK;
  const unsigned i010 = (hx0 ^ hy1 ^ hz0) & TMASK;
  const unsigned i011 = (hx0 ^ hy1 ^ hz1) & TMASK;
  const unsigned i100 = (hx1 ^ hy0 ^ hz0) & TMASK;
  const unsigned i101 = (hx1 ^ hy0 ^ hz1) & TMASK;
  const unsigned i110 = (hx1 ^ hy1 ^ hz0) & TMASK;
  const unsigned i111 = (hx1 ^ hy1 ^ hz1) & TMASK;

  const float2 e000 = tb[i000];
  const float2 e001 = tb[i001];
  const float2 e010 = tb[i010];
  const float2 e011 = tb[i011];
  const float2 e100 = tb[i100];
  const float2 e101 = tb[i101];
  const float2 e110 = tb[i110];
  const float2 e111 = tb[i111];

  const float ax = 1.0f - dx, ay = 1.0f - dy, az = 1.0f - dz;
  const float w00 = ax * ay, w01 = ax * dy, w10 = dx * ay, w11 = dx * dy;
  const float w000 = w00 * az, w001 = w00 * dz;
  const float w010 = w01 * az, w011 = w01 * dz;
  const float w100 = w10 * az, w101 = w10 * dz;
  const float w110 = w11 * az, w111 = w11 * dz;

  s0 = w000 * e000.x;
  s1 = w000 * e000.y;
  s0 = fmaf(w001, e001.x, s0); s1 = fmaf(w001, e001.y, s1);
  s0 = fmaf(w010, e010.x, s0); s1 = fmaf(w010, e010.y, s1);
  s0 = fmaf(w011, e011.x, s0); s1 = fmaf(w011, e011.y, s1);
  s0 = fmaf(w100, e100.x, s0); s1 = fmaf(w100, e100.y, s1);
  s0 = fmaf(w101, e101.x, s0); s1 = fmaf(w101, e101.y, s1);
  s0 = fmaf(w110, e110.x, s0); s1 = fmaf(w110, e110.y, s1);
  s0 = fmaf(w111, e111.x, s0); s1 = fmaf(w111, e111.y, s1);
}

// ---- Pass 1: level-major gather -> scratch [chunk][LVLS][256] float2 -------
__global__ __launch_bounds__(256) void hg_gather(
    const float* __restrict__ xyz,
    const float* __restrict__ tables,
    float2* __restrict__ scratch,
    int n, int nb, HGParams P) {
  const int lvl = blockIdx.x / nb;               // consecutive blocks share a level
  const int c   = blockIdx.x % nb;
  const int p   = c * 256 + threadIdx.x;
  if (p >= n) return;

  const float x = xyz[3 * (size_t)p + 0];
  const float y = xyz[3 * (size_t)p + 1];
  const float z = xyz[3 * (size_t)p + 2];

  const float2* __restrict__ tb = (const float2*)tables + (size_t)lvl * T_SZ;
  float s0, s1;
  encode_one_level(x, y, z, P.cell[lvl], P.inv[lvl], tb, s0, s1);
  // chunk-major: 2 KB contiguous per block write
  scratch[((size_t)c * LVLS + lvl) * 256 + threadIdx.x] = make_float2(s0, s1);
}

// ---- Pass 2: register-only transpose, thread = point -----------------------
__global__ __launch_bounds__(256) void hg_transpose_reg(
    const float2* __restrict__ sc,
    float4* __restrict__ out4, int n) {
  const int p = blockIdx.x * 256 + threadIdx.x;
  if (p >= n) return;
  const int c = p >> 8;                          // chunk
  const int t = p & 255;                         // point within chunk
  const size_t base = ((size_t)c * LVLS) * 256 + t;

  float2 v[LVLS];
#pragma unroll
  for (int l = 0; l < LVLS; ++l)                 // lane-consecutive 8B loads
    v[l] = sc[base + (size_t)l * 256];

  const size_t ob = (size_t)p * 8;               // thread owns its 128B row
#pragma unroll
  for (int j = 0; j < 8; ++j)
    out4[ob + j] = make_float4(v[2 * j].x, v[2 * j].y,
                               v[2 * j + 1].x, v[2 * j + 1].y);
}

// ---- Fallback: point-major (only if ws too small) --------------------------
__global__ __launch_bounds__(256) void hg_encode(
    const float* __restrict__ xyz,
    const float* __restrict__ tables,
    float* __restrict__ out,
    int n, HGParams P) {
  int p = blockIdx.x * 256 + threadIdx.x;
  if (p >= n) return;
  const float x = xyz[3 * (size_t)p + 0];
  const float y = xyz[3 * (size_t)p + 1];
  const float z = xyz[3 * (size_t)p + 2];
  float o[2 * LVLS];
#pragma unroll
  for (int l = 0; l < LVLS; ++l) {
    const float2* __restrict__ tb = (const float2*)tables + (size_t)l * T_SZ;
    float s0, s1;
    encode_one_level(x, y, z, P.cell[l], P.inv[l], tb, s0, s1);
    o[2 * l + 0] = s0;
    o[2 * l + 1] = s1;
  }
  float4* o4 = (float4*)(out + (size_t)p * (2 * LVLS));
#pragma unroll
  for (int i = 0; i < 8; ++i)
    o4[i] = make_float4(o[4 * i + 0], o[4 * i + 1], o[4 * i + 2], o[4 * i + 3]);
}

extern "C" void kernel_launch(void* const* d_in, const int* in_sizes, int n_in,
                              void* d_out, int out_size, void* d_ws, size_t ws_size,
                              hipStream_t stream) {
  const float* xyz    = (const float*)d_in[0];
  const float* tables = (const float*)d_in[1];
  float* out = (float*)d_out;
  const int n = in_sizes[0] / 3;

  // Replicate Python's RES computation bit-for-bit (same glibc libm doubles).
  HGParams P;
  const double B = exp((log(2048.0) - log(16.0)) / 15.0);
  for (int i = 0; i < LVLS; ++i) {
    const int r = (int)floor(16.0 * pow(B, (double)i));
    const double cd = 2.0 / (double)r;
    P.cell[i] = (float)cd;
    P.inv[i]  = 1.0f / P.cell[i];
  }

  const int nc = (n + 255) / 256;                // 256-pt chunks
  const size_t need = (size_t)nc * LVLS * 256 * sizeof(float2);
  if (ws_size >= need) {
    hg_gather<<<dim3(LVLS * nc), 256, 0, stream>>>(
        xyz, tables, (float2*)d_ws, n, nc, P);
    hg_transpose_reg<<<nc, 256, 0, stream>>>(
        (const float2*)d_ws, (float4*)out, n);
  } else {
    hg_encode<<<(n + 255) / 256, 256, 0, stream>>>(xyz, tables, out, n, P);
  }
}